// Round 17
// baseline (415.070 us; speedup 1.0000x reference)
//
#include <hip/hip_runtime.h>
#include <hip/hip_bf16.h>

#define E_DIM 1024
#define HEADS 16
#define DHEAD 64
#define RANK 8
#define BATCH 4
#define SEQ 4096
#define MTOT (BATCH*SEQ)

typedef short bf16x8 __attribute__((ext_vector_type(8)));
typedef float f32x4  __attribute__((ext_vector_type(4)));

__device__ __forceinline__ float bf2f(unsigned short u) {
    return __uint_as_float(((unsigned int)u) << 16);
}
__device__ __forceinline__ unsigned short f2bf(float f) {
    unsigned int x = __float_as_uint(f);
    unsigned int r = (x + 0x7fffu + ((x >> 16) & 1u)) >> 16;
    return (unsigned short)r;
}
__device__ __forceinline__ unsigned int pack2bf(float lo, float hi) {
    unsigned int l = __float_as_uint(lo), h = __float_as_uint(hi);
    return ((h + 0x8000u) & 0xFFFF0000u) | ((l + 0x8000u) >> 16);
}
// single-instruction packed f32x2 -> bf16x2 (RNE), lo -> low half
__device__ __forceinline__ unsigned int cvt2bf(float lo, float hi) {
    unsigned int r;
    asm("v_cvt_pk_bf16_f32 %0, %1, %2" : "=v"(r) : "v"(lo), "v"(hi));
    return r;
}
__device__ __forceinline__ void async16(const void* g, void* l) {
    __builtin_amdgcn_global_load_lds(
        (const __attribute__((address_space(1))) unsigned int*)g,
        (__attribute__((address_space(3))) unsigned int*)l, 16, 0, 0);
}

// ---------------------------------------------------------------------------
__global__ __launch_bounds__(256)
void ws_sentinel(float* __restrict__ out, float mb)
{
    out[threadIdx.x] = mb;
}

__global__ __launch_bounds__(256)
void zero_colsum(float* __restrict__ p)
{
    p[blockIdx.x * 256 + threadIdx.x] = 0.f;
}

// ---------------------------------------------------------------------------
// convert q/k/v f32 -> bf16 once. Blocks 0-15 also zero colsum.
// ---------------------------------------------------------------------------
__global__ __launch_bounds__(256)
void convert_bf16(const float* __restrict__ q, const float* __restrict__ k,
                  const float* __restrict__ v, unsigned short* __restrict__ qb,
                  unsigned short* __restrict__ kb, unsigned short* __restrict__ vb,
                  float* __restrict__ colsum)
{
    if (blockIdx.x < 16)
        colsum[blockIdx.x * 256 + threadIdx.x] = 0.f;
    const size_t stride = (size_t)gridDim.x * 256;
    for (size_t idx = (size_t)blockIdx.x * 256 + threadIdx.x; idx < 3u*2097152u; idx += stride) {
        const int g = (int)(idx >> 21);                 // 0..2
        const size_t off = (idx & 2097151u) * 8;
        const float* src = (g == 0) ? q : (g == 1) ? k : v;
        unsigned short* dst = (g == 0) ? qb : (g == 1) ? kb : vb;
        float4 a = *(const float4*)(src + off);
        float4 b = *(const float4*)(src + off + 4);
        uint4 o;
        o.x = cvt2bf(a.x, a.y); o.y = cvt2bf(a.z, a.w);
        o.z = cvt2bf(b.x, b.y); o.w = cvt2bf(b.z, b.w);
        *(uint4*)(dst + off) = o;
    }
}

// ---------------------------------------------------------------------------
// K1: Wt[g][n][k] = bf16( W[g][k][n] + sum_r A[g][k][r] B[g][r][n] )
// ---------------------------------------------------------------------------
__global__ __launch_bounds__(256)
void prep_weights_t(const float* __restrict__ Wq, const float* __restrict__ Wk,
                    const float* __restrict__ Wv, const float* __restrict__ Wo,
                    const float* __restrict__ qa, const float* __restrict__ qb,
                    const float* __restrict__ ka, const float* __restrict__ kb,
                    const float* __restrict__ va, const float* __restrict__ vb,
                    unsigned short* __restrict__ Wt)
{
    __shared__ float tile[32][33];
    const int n0 = blockIdx.x * 32;
    const int k0 = blockIdx.y * 32;
    const int g  = blockIdx.z;
    const float* W = (g==0)?Wq:(g==1)?Wk:(g==2)?Wv:Wo;
    const float* A = (g==0)?qa:(g==1)?ka:va;
    const float* Bm= (g==0)?qb:(g==1)?kb:vb;
    const int t  = threadIdx.x;
    const int r  = t >> 3;
    const int c4 = (t & 7) * 4;

    float4 v = *(const float4*)(W + (size_t)(k0 + r)*E_DIM + n0 + c4);
    float o0=v.x, o1=v.y, o2=v.z, o3=v.w;
    if (g < 3) {
        #pragma unroll
        for (int rr = 0; rr < RANK; ++rr) {
            float av = A[(k0 + r)*RANK + rr];
            const float* bp = Bm + (size_t)rr*E_DIM + n0 + c4;
            o0 = fmaf(av, bp[0], o0);
            o1 = fmaf(av, bp[1], o1);
            o2 = fmaf(av, bp[2], o2);
            o3 = fmaf(av, bp[3], o3);
        }
    }
    tile[r][c4+0]=o0; tile[r][c4+1]=o1; tile[r][c4+2]=o2; tile[r][c4+3]=o3;
    __syncthreads();
    union { unsigned short h[4]; uint2 u; } o;
    #pragma unroll
    for (int i = 0; i < 4; ++i) o.h[i] = f2bf(tile[c4+i][r]);
    *(uint2*)(Wt + (size_t)g*1048576 + (size_t)(n0 + r)*E_DIM + k0 + c4) = o.u;
}

// ---------------------------------------------------------------------------
// GEMM core: C[64,128] tile, BK=64, single-buffer 2-barrier, 4 waves 2x2.
// bf16 path (XF32=0): A fragments loaded DIRECT global->reg (derivation:
//   LDS[row][slot]=X[row][k0+(slot^(row&7))*8], read slot=(h*4+lg)^(row&7)
//   => frag = X[(i0+row)*1024 + k0 + (h*4+lg)*8]; lanes lg=0..3 cover one
//   64B line per row -> coalesced). LDS holds only B (16 KB) -> LDS traffic
//   per K-step 72KB -> 48KB (was LDS-BW-bound at ~80% busy).
// XF32=1 fallback: old reg-staged A + cvt_pk (24 KB LDS).
// mode 1: fused q-softmax. mode 2: K transpose write + exp-colsum atomics.
// mode 3: V transpose write. mode 4: B batched by i0>>12 (final proj).
// ---------------------------------------------------------------------------
template<int XF32, int OUTF32>
__device__ __forceinline__
void gemm_core(unsigned short* SH, const void* __restrict__ Xv,
               const unsigned short* __restrict__ Wt,
               const float* __restrict__ bias, void* __restrict__ outv,
               const unsigned char* __restrict__ maskp,
               float* __restrict__ colsum, int mode, int i0, int j0)
{
    unsigned short* const As = SH;                       // XF32 only (8 KB)
    unsigned short* const Bs = XF32 ? SH + 4096 : SH;    // 16 KB
    const int tid  = threadIdx.x;
    const int lane = tid & 63;
    const int w    = tid >> 6;
    const int wr   = w >> 1, wc = w & 1;
    const int l15  = lane & 15, lg = lane >> 4;
    const int srow8  = lane >> 3;
    const int schunk = (lane & 7) ^ srow8;

    const unsigned short* Wb = (mode == 4) ? Wt + (((size_t)(i0 >> 12)) << 20) : Wt;
    const float* Xf = (const float*)Xv;
    const unsigned short* Xh = (const unsigned short*)Xv;

    f32x4 acc[2][4];
    #pragma unroll
    for (int m = 0; m < 2; ++m)
        #pragma unroll
        for (int n = 0; n < 4; ++n) {
            f32x4 z = {0.f, 0.f, 0.f, 0.f};
            acc[m][n] = z;
        }

    for (int k0 = 0; k0 < E_DIM; k0 += 64) {
        // ---- stage B: 128 n-rows x 64 k (always LDS via gload_lds) ----
        #pragma unroll
        for (int c = 0; c < 4; ++c) {
            const int rbase = c*32 + w*8;
            async16(Wb + (size_t)(j0 + rbase + srow8)*E_DIM + k0 + schunk*8,
                    &Bs[rbase*64]);
        }
        // ---- A operand ----
        bf16x8 areg[2][2];                  // [half][mt], direct-global path
        if (XF32) {
            const int arow = tid >> 2, q = tid & 3;       // 16 f32 per thread
            const float* xp = Xf + (size_t)(i0 + arow)*E_DIM + k0 + q*16;
            float4 u0 = *(const float4*)(xp);
            float4 u1 = *(const float4*)(xp + 4);
            float4 u2 = *(const float4*)(xp + 8);
            float4 u3 = *(const float4*)(xp + 12);
            uint4 p0, p1;
            p0.x = cvt2bf(u0.x, u0.y); p0.y = cvt2bf(u0.z, u0.w);
            p0.z = cvt2bf(u1.x, u1.y); p0.w = cvt2bf(u1.z, u1.w);
            p1.x = cvt2bf(u2.x, u2.y); p1.y = cvt2bf(u2.z, u2.w);
            p1.z = cvt2bf(u3.x, u3.y); p1.w = cvt2bf(u3.z, u3.w);
            const int swz = arow & 7;
            *(uint4*)&As[arow*64 + (((q*2    ) ^ swz))*8] = p0;
            *(uint4*)&As[arow*64 + (((q*2 + 1) ^ swz))*8] = p1;
        } else {
            #pragma unroll
            for (int half = 0; half < 2; ++half)
                #pragma unroll
                for (int mt = 0; mt < 2; ++mt) {
                    const int row = wr*32 + mt*16 + l15;
                    areg[half][mt] = *(const bf16x8*)
                        (Xh + (size_t)(i0 + row)*E_DIM + k0 + (half*4 + lg)*8);
                }
        }
        __syncthreads();                   // drains gload_lds + A loads
        // ---- compute: 2 halves x (B ds_reads + 8 MFMA) ----
        #pragma unroll
        for (int half = 0; half < 2; ++half) {
            bf16x8 a[2], b[4];
            #pragma unroll
            for (int mt = 0; mt < 2; ++mt) {
                if (XF32) {
                    const int row = wr*32 + mt*16 + l15;
                    a[mt] = *(const bf16x8*)&As[row*64 + (((half*4 + lg) ^ (row & 7)))*8];
                } else {
                    a[mt] = areg[half][mt];
                }
            }
            #pragma unroll
            for (int nt = 0; nt < 4; ++nt) {
                const int row = wc*64 + nt*16 + l15;
                b[nt] = *(const bf16x8*)&Bs[row*64 + (((half*4 + lg) ^ (row & 7)))*8];
            }
            #pragma unroll
            for (int mt = 0; mt < 2; ++mt)
                #pragma unroll
                for (int nt = 0; nt < 4; ++nt)
                    acc[mt][nt] = __builtin_amdgcn_mfma_f32_16x16x32_bf16(a[mt], b[nt], acc[mt][nt], 0, 0, 0);
        }
        __syncthreads();
    }

    // ---- epilogues. C/D: col=lane&15, row=(lane>>4)*4+reg ----
    float bv[4];
    #pragma unroll
    for (int n = 0; n < 4; ++n) bv[n] = bias[j0 + wc*64 + n*16 + l15];

    if (mode == 2 || mode == 3) {
        __syncthreads();                  // all ds_reads done before SH reuse
        float psum[4] = {0.f, 0.f, 0.f, 0.f};
        #pragma unroll
        for (int mt = 0; mt < 2; ++mt) {
            #pragma unroll
            for (int r = 0; r < 4; ++r) {
                const int ss = wr*32 + mt*16 + lg*4 + r;           // 0..63
                const bool mk = (mode == 2) ? (maskp[i0 + ss] != 0) : false;
                #pragma unroll
                for (int nt = 0; nt < 4; ++nt) {
                    float v = acc[mt][nt][r] + bv[nt];
                    if (mode == 2 && !mk) psum[nt] += __expf(v);
                    const int jj = wc*64 + nt*16 + l15;            // 0..127
                    SH[jj*64 + (((ss >> 3) ^ (jj & 7)))*8 + (ss & 7)] = f2bf(v);
                }
            }
        }
        if (mode == 2) {
            const int b = i0 >> 12;
            #pragma unroll
            for (int nt = 0; nt < 4; ++nt) {
                float s = psum[nt];
                s += __shfl_xor(s, 16);
                s += __shfl_xor(s, 32);
                if (lg == 0)
                    atomicAdd(&colsum[b*E_DIM + j0 + wc*64 + nt*16 + l15], s);
            }
        }
        __syncthreads();
        const int b = i0 >> 12, srel = i0 & 4095;
        unsigned short* T = (unsigned short*)outv;
        const int jj = tid >> 1, hf = tid & 1;
        const size_t gbase = ((size_t)(b*1024 + j0 + jj))*4096 + srel;
        #pragma unroll
        for (int c = 0; c < 4; ++c) {
            const int slot = hf*4 + c;
            uint4 u = *(const uint4*)&SH[jj*64 + ((slot ^ (jj & 7)))*8];
            *(uint4*)(T + gbase + slot*8) = u;
        }
        return;
    }

    #pragma unroll
    for (int mt = 0; mt < 2; ++mt) {
        #pragma unroll
        for (int r = 0; r < 4; ++r) {
            float v0 = acc[mt][0][r] + bv[0];
            float v1 = acc[mt][1][r] + bv[1];
            float v2 = acc[mt][2][r] + bv[2];
            float v3 = acc[mt][3][r] + bv[3];
            if (mode == 1) {
                float mx = fmaxf(fmaxf(v0, v1), fmaxf(v2, v3));
                mx = fmaxf(mx, __shfl_xor(mx, 1));
                mx = fmaxf(mx, __shfl_xor(mx, 2));
                mx = fmaxf(mx, __shfl_xor(mx, 4));
                mx = fmaxf(mx, __shfl_xor(mx, 8));
                v0 = __expf(v0 - mx); v1 = __expf(v1 - mx);
                v2 = __expf(v2 - mx); v3 = __expf(v3 - mx);
                float s = v0 + v1 + v2 + v3;
                s += __shfl_xor(s, 1);
                s += __shfl_xor(s, 2);
                s += __shfl_xor(s, 4);
                s += __shfl_xor(s, 8);
                float inv = 1.f / s;
                v0 *= inv; v1 *= inv; v2 *= inv; v3 *= inv;
            }
            const size_t rowo = (size_t)(i0 + wr*32 + mt*16 + lg*4 + r) * E_DIM;
            const int colb = j0 + wc*64 + l15;
            if (OUTF32) {
                float* out = (float*)outv;
                out[rowo + colb     ] = v0;
                out[rowo + colb + 16] = v1;
                out[rowo + colb + 32] = v2;
                out[rowo + colb + 48] = v3;
            } else {
                unsigned short* out = (unsigned short*)outv;
                out[rowo + colb     ] = f2bf(v0);
                out[rowo + colb + 16] = f2bf(v1);
                out[rowo + colb + 32] = f2bf(v2);
                out[rowo + colb + 48] = f2bf(v3);
            }
        }
    }
}

// ---------------------------------------------------------------------------
// Dispatch swizzle (verified r12: FETCH 804 -> 140 MB): for linear id n,
// panel = (n>>6)*8 + (n&7); j = (n>>3)&7  -> a panel's 8 j-blocks share an
// XCD (id mod 8) and a 64-id temporal window (co-resident).
// ---------------------------------------------------------------------------

// single-GEMM wrapper (final projection, bf16 A, mode 4). 1D grid 2048.
template<int XF32, int OUTF32>
__global__ __launch_bounds__(256)
void mfma_gemm(const void* __restrict__ Xv, const unsigned short* __restrict__ Wt,
               const float* __restrict__ bias, void* __restrict__ outv,
               const unsigned char* __restrict__ maskp, float* __restrict__ colsum,
               int mode)
{
    __shared__ __align__(16) unsigned short SH[XF32 ? 12288 : 8192];
    const int n = blockIdx.x;
    const int panel = ((n >> 6) << 3) | (n & 7);    // 0..255
    const int jj = (n >> 3) & 7;
    gemm_core<XF32, OUTF32>(SH, Xv, Wt, bias, outv, maskp, colsum, mode,
                            panel * 64, jj * 128);
}

// fused q/k/v projection: 1D grid 6144; panel 0..767 -> grp, ip
template<int XF32>
__global__ __launch_bounds__(256)
void proj_fused(const void* __restrict__ Xq, const void* __restrict__ Xk,
                const void* __restrict__ Xvv, const unsigned short* __restrict__ Wt,
                const float* __restrict__ bq, const float* __restrict__ bk,
                const float* __restrict__ bv, unsigned short* __restrict__ qn,
                unsigned short* __restrict__ KT, unsigned short* __restrict__ VT,
                const unsigned char* __restrict__ mask, float* __restrict__ colsum)
{
    __shared__ __align__(16) unsigned short SH[XF32 ? 12288 : 8192];
    const int n = blockIdx.x;
    const int panel = ((n >> 6) << 3) | (n & 7);    // 0..767
    const int jj = (n >> 3) & 7;
    const int grp = panel >> 8;
    const int ip  = panel & 255;
    const void* X = (grp == 0) ? Xq : (grp == 1) ? Xk : Xvv;
    const float* bias = (grp == 0) ? bq : (grp == 1) ? bk : bv;
    void* out = (grp == 0) ? (void*)qn : (grp == 1) ? (void*)KT : (void*)VT;
    gemm_core<XF32, 0>(SH, X, Wt + (size_t)grp*1048576, bias, out, mask, colsum,
                       grp + 1, ip * 64, jj * 128);
}

// ---------------------------------------------------------------------------
// context via MFMA: partial[sb][b][h][d][e] over 512-s chunks (8 planes)
// ---------------------------------------------------------------------------
__global__ __launch_bounds__(256)
void context_mfma(const unsigned short* __restrict__ KT,
                  const unsigned short* __restrict__ VT,
                  const unsigned char* __restrict__ mask,
                  float* __restrict__ partial)
{
    __shared__ __align__(16) unsigned short Ks[64*128];
    __shared__ __align__(16) unsigned short Vs[64*128];
    const int sb = blockIdx.x, h = blockIdx.y, b = blockIdx.z;
    const int tid = threadIdx.x, lane = tid & 63, w = tid >> 6;
    const int wr = w >> 1, wc = w & 1;
    const int l15 = lane & 15, lg = lane >> 4;
    const int srow = tid >> 2;
    const int sq0  = (tid & 3) * 4;

    f32x4 acc[2][2];
    #pragma unroll
    for (int m = 0; m < 2; ++m)
        #pragma unroll
        for (int n = 0; n < 2; ++n) {
            f32x4 z = {0.f, 0.f, 0.f, 0.f};
            acc[m][n] = z;
        }

    for (int st = 0; st < 4; ++st) {
        const int s0 = sb*512 + st*128;
        const unsigned short* kt = KT + ((size_t)(b*1024 + h*64 + srow))*4096 + s0;
        const unsigned short* vt = VT + ((size_t)(b*1024 + h*64 + srow))*4096 + s0;
        const unsigned char*  mp = mask + b*SEQ + s0;
        #pragma unroll
        for (int qi = 0; qi < 4; ++qi) {
            const int slot = sq0 + qi;
            uint4 u = *(const uint4*)(kt + slot*8);
            uint2 mk = *(const uint2*)(mp + slot*8);
            const unsigned char* mb = (const unsigned char*)&mk;
            const unsigned short* us = (const unsigned short*)&u;
            float e[8];
            #pragma unroll
            for (int i = 0; i < 8; ++i)
                e[i] = mb[i] ? 0.f : __expf(bf2f(us[i]));
            uint4 p;
            p.x = pack2bf(e[0], e[1]);
            p.y = pack2bf(e[2], e[3]);
            p.z = pack2bf(e[4], e[5]);
            p.w = pack2bf(e[6], e[7]);
            *(uint4*)&Ks[srow*128 + ((slot ^ (srow & 15)))*8] = p;
            uint4 uv = *(const uint4*)(vt + slot*8);
            *(uint4*)&Vs[srow*128 + ((slot ^ (srow & 15)))*8] = uv;
        }
        __syncthreads();
        #pragma unroll
        for (int ks = 0; ks < 4; ++ks) {
            bf16x8 a[2], bq[2];
            #pragma unroll
            for (int mt = 0; mt < 2; ++mt) {
                const int d = wr*32 + mt*16 + l15;
                a[mt] = *(const bf16x8*)&Ks[d*128 + (((ks*4+lg) ^ (d & 15)))*8];
            }
            #pragma unroll
            for (int nt = 0; nt < 2; ++nt) {
                const int e = wc*32 + nt*16 + l15;
                bq[nt] = *(const bf16x8*)&Vs[e*128 + (((ks*4+lg) ^ (e & 15)))*8];
            }
            #pragma unroll
            for (int mt = 0; mt < 2; ++mt)
                #pragma unroll
                for (int nt = 0; nt < 2; ++nt)
                    acc[mt][nt] = __builtin_amdgcn_mfma_f32_16x16x32_bf16(a[mt], bq[nt], acc[mt][nt], 0, 0, 0);
        }
        __syncthreads();
    }
    float* pp = partial + (size_t)sb*(BATCH*HEADS*4096) + ((size_t)(b*HEADS + h))*4096;
    #pragma unroll
    for (int mt = 0; mt < 2; ++mt)
        #pragma unroll
        for (int nt = 0; nt < 2; ++nt)
            #pragma unroll
            for (int r = 0; r < 4; ++r) {
                const int d = wr*32 + mt*16 + lg*4 + r;
                const int e = wc*32 + nt*16 + l15;
                pp[d*64 + e] = acc[mt][nt][r];
            }
}

// ---------------------------------------------------------------------------
__global__ __launch_bounds__(256)
void reduce_ctx(const float* __restrict__ partial, float* __restrict__ ctx)
{
    const int i = blockIdx.x * 256 + threadIdx.x;
    const float4* p = (const float4*)partial;
    float4 s = p[i];
    #pragma unroll
    for (int q = 1; q < 8; ++q) {
        float4 u = p[(size_t)q*65536 + i];
        s.x += u.x; s.y += u.y; s.z += u.z; s.w += u.w;
    }
    ((float4*)ctx)[i] = s;
}

// ---------------------------------------------------------------------------
// G_t[b][j][h*64+d] = sum_e WtO[j][h*64+e] * (ctx[b,h,d,e]/colsum[b,h,d])
// ---------------------------------------------------------------------------
__global__ __launch_bounds__(256)
void g_kernel(const unsigned short* __restrict__ WtO, const float* __restrict__ ctx,
              const float* __restrict__ colsum, unsigned short* __restrict__ Gt)
{
    __shared__ __align__(16) unsigned short Aw[128*64];
    __shared__ __align__(16) unsigned short Bc[64*64];
    const int jt = blockIdx.x, h = blockIdx.y, b = blockIdx.z;
    const int tid = threadIdx.x, lane = tid & 63, w = tid >> 6;
    const int l15 = lane & 15, lg = lane >> 4;
    const int j0 = jt * 128;

    {
        const int ar = tid >> 1, aq0 = (tid & 1) * 4;
        #pragma unroll
        for (int qi = 0; qi < 4; ++qi) {
            const int slot = aq0 + qi;
            uint4 u = *(const uint4*)(WtO + (size_t)(j0 + ar)*E_DIM + h*64 + slot*8);
            *(uint4*)&Aw[ar*64 + ((slot ^ (ar & 7)))*8] = u;
        }
    }
    {
        const int br = tid >> 2, bq0 = (tid & 3) * 2;
        const float inv = 1.f / colsum[b*E_DIM + h*64 + br];
        #pragma unroll
        for (int qi = 0; qi < 2; ++qi) {
            const int slot = bq0 + qi;
            const float* cp = ctx + (((size_t)(b*HEADS + h))*64 + br)*64 + slot*8;
            float4 c0 = *(const float4*)cp;
            float4 c1 = *(const float4*)(cp + 4);
            uint4 p;
            p.x = pack2bf(c0.x*inv, c0.y*inv);
            p.y = pack2bf(c0.z*inv, c0.w*inv);
            p.z = pack2bf(c1.x*inv, c1.y*inv);
            p.w = pack2bf(c1.z*inv, c1.w*inv);
            *(uint4*)&Bc[br*64 + ((slot ^ (br & 7)))*8] = p;
        }
    }
    __syncthreads();

    f32x4 acc[2][4];
    #pragma unroll
    for (int m = 0; m < 2; ++m)
        #pragma unroll
        for (int n = 0; n < 4; ++n) {
            f32x4 z = {0.f, 0.f, 0.f, 0.f};
            acc[m][n] = z;
        }
    #pragma unroll
    for (int ks = 0; ks < 2; ++ks) {
        bf16x8 a[2], bv[4];
        #pragma unroll
        for (int mt = 0; mt < 2; ++mt) {
            const int jr = w*32 + mt*16 + l15;
            a[mt] = *(const bf16x8*)&Aw[jr*64 + (((ks*4+lg) ^ (jr & 7)))*8];
        }
        #pragma unroll
        for (int nt = 0; nt < 4; ++nt) {
            const int d = nt*16 + l15;
            bv[nt] = *(const bf16x8*)&Bc[d*64 + (((ks*4+lg) ^ (d & 7)))*8];
        }
        #pragma unroll
        for (int mt = 0; mt < 2; ++mt)
            #pragma unroll
            for (int nt = 0; nt < 4; ++nt)
                acc[mt][nt] = __builtin_amdgcn_mfma_f32_16x16x32_bf16(a[mt], bv[nt], acc[mt][nt], 0, 0, 0);
    }
    #pragma unroll
    for (int mt = 0; mt < 2; ++mt)
        #pragma unroll
        for (int nt = 0; nt < 4; ++nt)
            #pragma unroll
            for (int r = 0; r < 4; ++r) {
                const int j = j0 + w*32 + mt*16 + lg*4 + r;
                const int d = nt*16 + l15;
                Gt[(size_t)b*1048576 + (size_t)j*E_DIM + h*64 + d] = f2bf(acc[mt][nt][r]);
            }
}

// ---------------------------------------------------------------------------
extern "C" void kernel_launch(void* const* d_in, const int* in_sizes, int n_in,
                              void* d_out, int out_size, void* d_ws, size_t ws_size,
                              hipStream_t stream)
{
    const float* query = (const float*)d_in[0];
    const float* key   = (const float*)d_in[1];
    const float* value = (const float*)d_in[2];
    const unsigned char* mask = (const unsigned char*)d_in[3];
    const float* Wq  = (const float*)d_in[4];
    const float* bq  = (const float*)d_in[5];
    const float* Wk  = (const float*)d_in[6];
    const float* bk  = (const float*)d_in[7];
    const float* Wv  = (const float*)d_in[8];
    const float* bv_ = (const float*)d_in[9];
    const float* qla = (const float*)d_in[10];
    const float* qlb = (const float*)d_in[11];
    const float* kla = (const float*)d_in[12];
    const float* klb = (const float*)d_in[13];
    const float* vla = (const float*)d_in[14];
    const float* vlb = (const float*)d_in[15];
    const float* Wo  = (const float*)d_in[16];
    const float* bo  = (const float*)d_in[17];

    const size_t NEEDED_A = 118505472ULL;                 // base layout (proven)
    const size_t NEEDED_B = NEEDED_A + 3ULL*33554432ULL;  // + qbf/kbf/vbf
    if (ws_size < NEEDED_A) {
        ws_sentinel<<<1, 256, 0, stream>>>((float*)d_out, (float)(ws_size >> 20));
        return;
    }

    char* ws = (char*)d_ws;
    unsigned short* Wt      = (unsigned short*)(ws + 0);          // 8 MB
    unsigned short* KT      = (unsigned short*)(ws + 8388608);    // 32 MB [b][1024][4096]
    unsigned short* VT      = (unsigned short*)(ws + 41943040);   // 32 MB
    unsigned short* qn      = (unsigned short*)(ws + 75497472);   // 32 MB
    float*          partial = (float*)(ws + 109051904);           // 8 MB (dead before Gt)
    unsigned short* Gt      = (unsigned short*)(ws + 109051904);  // 8 MB (overlays partial)
    float*          colsum  = (float*)(ws + 117440512);           // 16 KB
    float*          ctx     = (float*)(ws + 117456896);           // 1 MB
    unsigned short* qbf     = (unsigned short*)(ws + 118505472);  // 32 MB (path B only)
    unsigned short* kbf     = (unsigned short*)(ws + 152059904);  // 32 MB
    unsigned short* vbf     = (unsigned short*)(ws + 185614336);  // 32 MB

    prep_weights_t<<<dim3(32, 32, 4), 256, 0, stream>>>(Wq, Wk, Wv, Wo,
                                                        qla, qlb, kla, klb, vla, vlb, Wt);
    if (ws_size >= NEEDED_B) {
        // path B: one-time f32->bf16 convert (+colsum zero), all-bf16 GEMMs
        convert_bf16<<<2048, 256, 0, stream>>>(query, key, value, qbf, kbf, vbf, colsum);
        proj_fused<0><<<6144, 256, 0, stream>>>(qbf, kbf, vbf, Wt,
                                                bq, bk, bv_, qn, KT, VT, mask, colsum);
    } else {
        // path A: f32 A staged in-GEMM via cvt_pk (r12-class fallback)
        zero_colsum<<<16, 256, 0, stream>>>(colsum);
        proj_fused<1><<<6144, 256, 0, stream>>>(query, key, value, Wt,
                                                bq, bk, bv_, qn, KT, VT, mask, colsum);
    }
    context_mfma<<<dim3(8, HEADS, BATCH), 256, 0, stream>>>(KT, VT, mask, partial);
    reduce_ctx<<<256, 256, 0, stream>>>(partial, ctx);
    g_kernel<<<dim3(8, HEADS, BATCH), 256, 0, stream>>>(Wt + 3145728, ctx, colsum, Gt);
    mfma_gemm<0, 1><<<2048, 256, 0, stream>>>(qn, Gt, bo, (float*)d_out,
                                              nullptr, nullptr, 4);
}

// Round 18
// 283.900 us; speedup vs baseline: 1.4620x; 1.4620x over previous
//
#include <hip/hip_runtime.h>
#include <hip/hip_bf16.h>

#define E_DIM 1024
#define HEADS 16
#define DHEAD 64
#define RANK 8
#define BATCH 4
#define SEQ 4096
#define MTOT (BATCH*SEQ)

typedef short bf16x8 __attribute__((ext_vector_type(8)));
typedef float f32x4  __attribute__((ext_vector_type(4)));

__device__ __forceinline__ float bf2f(unsigned short u) {
    return __uint_as_float(((unsigned int)u) << 16);
}
__device__ __forceinline__ unsigned short f2bf(float f) {
    unsigned int x = __float_as_uint(f);
    unsigned int r = (x + 0x7fffu + ((x >> 16) & 1u)) >> 16;
    return (unsigned short)r;
}
__device__ __forceinline__ unsigned int pack2bf(float lo, float hi) {
    unsigned int l = __float_as_uint(lo), h = __float_as_uint(hi);
    return ((h + 0x8000u) & 0xFFFF0000u) | ((l + 0x8000u) >> 16);
}
// single-instruction packed f32x2 -> bf16x2 (RNE), lo -> low half
__device__ __forceinline__ unsigned int cvt2bf(float lo, float hi) {
    unsigned int r;
    asm("v_cvt_pk_bf16_f32 %0, %1, %2" : "=v"(r) : "v"(lo), "v"(hi));
    return r;
}
__device__ __forceinline__ void async16(const void* g, void* l) {
    __builtin_amdgcn_global_load_lds(
        (const __attribute__((address_space(1))) unsigned int*)g,
        (__attribute__((address_space(3))) unsigned int*)l, 16, 0, 0);
}

// ---------------------------------------------------------------------------
__global__ __launch_bounds__(256)
void ws_sentinel(float* __restrict__ out, float mb)
{
    out[threadIdx.x] = mb;
}

__global__ __launch_bounds__(256)
void zero_colsum(float* __restrict__ p)
{
    p[blockIdx.x * 256 + threadIdx.x] = 0.f;
}

// ---------------------------------------------------------------------------
// convert q/k/v f32 -> bf16 once. Blocks 0-15 also zero colsum.
// ---------------------------------------------------------------------------
__global__ __launch_bounds__(256)
void convert_bf16(const float* __restrict__ q, const float* __restrict__ k,
                  const float* __restrict__ v, unsigned short* __restrict__ qb,
                  unsigned short* __restrict__ kb, unsigned short* __restrict__ vb,
                  float* __restrict__ colsum)
{
    if (blockIdx.x < 16)
        colsum[blockIdx.x * 256 + threadIdx.x] = 0.f;
    const size_t stride = (size_t)gridDim.x * 256;
    for (size_t idx = (size_t)blockIdx.x * 256 + threadIdx.x; idx < 3u*2097152u; idx += stride) {
        const int g = (int)(idx >> 21);                 // 0..2
        const size_t off = (idx & 2097151u) * 8;
        const float* src = (g == 0) ? q : (g == 1) ? k : v;
        unsigned short* dst = (g == 0) ? qb : (g == 1) ? kb : vb;
        float4 a = *(const float4*)(src + off);
        float4 b = *(const float4*)(src + off + 4);
        uint4 o;
        o.x = cvt2bf(a.x, a.y); o.y = cvt2bf(a.z, a.w);
        o.z = cvt2bf(b.x, b.y); o.w = cvt2bf(b.z, b.w);
        *(uint4*)(dst + off) = o;
    }
}

// ---------------------------------------------------------------------------
// K1: Wt[g][n][k] = bf16( W[g][k][n] + sum_r A[g][k][r] B[g][r][n] )
// ---------------------------------------------------------------------------
__global__ __launch_bounds__(256)
void prep_weights_t(const float* __restrict__ Wq, const float* __restrict__ Wk,
                    const float* __restrict__ Wv, const float* __restrict__ Wo,
                    const float* __restrict__ qa, const float* __restrict__ qb,
                    const float* __restrict__ ka, const float* __restrict__ kb,
                    const float* __restrict__ va, const float* __restrict__ vb,
                    unsigned short* __restrict__ Wt)
{
    __shared__ float tile[32][33];
    const int n0 = blockIdx.x * 32;
    const int k0 = blockIdx.y * 32;
    const int g  = blockIdx.z;
    const float* W = (g==0)?Wq:(g==1)?Wk:(g==2)?Wv:Wo;
    const float* A = (g==0)?qa:(g==1)?ka:va;
    const float* Bm= (g==0)?qb:(g==1)?kb:vb;
    const int t  = threadIdx.x;
    const int r  = t >> 3;
    const int c4 = (t & 7) * 4;

    float4 v = *(const float4*)(W + (size_t)(k0 + r)*E_DIM + n0 + c4);
    float o0=v.x, o1=v.y, o2=v.z, o3=v.w;
    if (g < 3) {
        #pragma unroll
        for (int rr = 0; rr < RANK; ++rr) {
            float av = A[(k0 + r)*RANK + rr];
            const float* bp = Bm + (size_t)rr*E_DIM + n0 + c4;
            o0 = fmaf(av, bp[0], o0);
            o1 = fmaf(av, bp[1], o1);
            o2 = fmaf(av, bp[2], o2);
            o3 = fmaf(av, bp[3], o3);
        }
    }
    tile[r][c4+0]=o0; tile[r][c4+1]=o1; tile[r][c4+2]=o2; tile[r][c4+3]=o3;
    __syncthreads();
    union { unsigned short h[4]; uint2 u; } o;
    #pragma unroll
    for (int i = 0; i < 4; ++i) o.h[i] = f2bf(tile[c4+i][r]);
    *(uint2*)(Wt + (size_t)g*1048576 + (size_t)(n0 + r)*E_DIM + k0 + c4) = o.u;
}

// ---------------------------------------------------------------------------
// GEMM core: C[64,128] tile, BK=64, single-buffer 2-barrier (r13/r16-proven),
// 4 waves 2x2 of 32x64, LDS 24 KB, slot-XOR swizzle ^ (row&7).
// XF32=1: f32 A staged via regs + cvt_pk (fallback path only).
// mode 1: fused q-softmax. mode 2: K transpose write + exp-colsum atomics.
// mode 3: V transpose write. mode 4: B batched by i0>>12 (final proj).
// ---------------------------------------------------------------------------
template<int XF32, int OUTF32>
__device__ __forceinline__
void gemm_core(unsigned short* SH, const void* __restrict__ Xv,
               const unsigned short* __restrict__ Wt,
               const float* __restrict__ bias, void* __restrict__ outv,
               const unsigned char* __restrict__ maskp,
               float* __restrict__ colsum, int mode, int i0, int j0)
{
    unsigned short* const As = SH;          // 64*64 shorts = 8 KB
    unsigned short* const Bs = SH + 4096;   // 128*64 shorts = 16 KB
    const int tid  = threadIdx.x;
    const int lane = tid & 63;
    const int w    = tid >> 6;
    const int wr   = w >> 1, wc = w & 1;
    const int l15  = lane & 15, lg = lane >> 4;
    const int srow8  = lane >> 3;
    const int schunk = (lane & 7) ^ srow8;

    const unsigned short* Wb = (mode == 4) ? Wt + (((size_t)(i0 >> 12)) << 20) : Wt;
    const float* Xf = (const float*)Xv;
    const unsigned short* Xh = (const unsigned short*)Xv;

    f32x4 acc[2][4];
    #pragma unroll
    for (int m = 0; m < 2; ++m)
        #pragma unroll
        for (int n = 0; n < 4; ++n) {
            f32x4 z = {0.f, 0.f, 0.f, 0.f};
            acc[m][n] = z;
        }

    for (int k0 = 0; k0 < E_DIM; k0 += 64) {
        // ---- stage A: 64 rows x 64 k ----
        if (XF32) {
            const int arow = tid >> 2, q = tid & 3;       // 16 f32 per thread
            const float* xp = Xf + (size_t)(i0 + arow)*E_DIM + k0 + q*16;
            float4 u0 = *(const float4*)(xp);
            float4 u1 = *(const float4*)(xp + 4);
            float4 u2 = *(const float4*)(xp + 8);
            float4 u3 = *(const float4*)(xp + 12);
            uint4 p0, p1;
            p0.x = cvt2bf(u0.x, u0.y); p0.y = cvt2bf(u0.z, u0.w);
            p0.z = cvt2bf(u1.x, u1.y); p0.w = cvt2bf(u1.z, u1.w);
            p1.x = cvt2bf(u2.x, u2.y); p1.y = cvt2bf(u2.z, u2.w);
            p1.z = cvt2bf(u3.x, u3.y); p1.w = cvt2bf(u3.z, u3.w);
            const int swz = arow & 7;
            *(uint4*)&As[arow*64 + (((q*2    ) ^ swz))*8] = p0;
            *(uint4*)&As[arow*64 + (((q*2 + 1) ^ swz))*8] = p1;
        } else {
            #pragma unroll
            for (int c = 0; c < 2; ++c) {
                const int rbase = c*32 + w*8;
                async16(Xh + (size_t)(i0 + rbase + srow8)*E_DIM + k0 + schunk*8,
                        &As[rbase*64]);
            }
        }
        // ---- stage B: 128 n-rows x 64 k ----
        #pragma unroll
        for (int c = 0; c < 4; ++c) {
            const int rbase = c*32 + w*8;
            async16(Wb + (size_t)(j0 + rbase + srow8)*E_DIM + k0 + schunk*8,
                    &Bs[rbase*64]);
        }
        __syncthreads();
        // ---- compute: 2 halves x (6 ds_read_b128 + 8 MFMA) ----
        #pragma unroll
        for (int half = 0; half < 2; ++half) {
            bf16x8 a[2], b[4];
            #pragma unroll
            for (int mt = 0; mt < 2; ++mt) {
                const int row = wr*32 + mt*16 + l15;
                a[mt] = *(const bf16x8*)&As[row*64 + (((half*4 + lg) ^ (row & 7)))*8];
            }
            #pragma unroll
            for (int nt = 0; nt < 4; ++nt) {
                const int row = wc*64 + nt*16 + l15;
                b[nt] = *(const bf16x8*)&Bs[row*64 + (((half*4 + lg) ^ (row & 7)))*8];
            }
            #pragma unroll
            for (int mt = 0; mt < 2; ++mt)
                #pragma unroll
                for (int nt = 0; nt < 4; ++nt)
                    acc[mt][nt] = __builtin_amdgcn_mfma_f32_16x16x32_bf16(a[mt], b[nt], acc[mt][nt], 0, 0, 0);
        }
        __syncthreads();
    }

    // ---- epilogues. C/D: col=lane&15, row=(lane>>4)*4+reg ----
    float bv[4];
    #pragma unroll
    for (int n = 0; n < 4; ++n) bv[n] = bias[j0 + wc*64 + n*16 + l15];

    if (mode == 2 || mode == 3) {
        __syncthreads();                  // all ds_reads done before SH reuse
        float psum[4] = {0.f, 0.f, 0.f, 0.f};
        #pragma unroll
        for (int mt = 0; mt < 2; ++mt) {
            #pragma unroll
            for (int r = 0; r < 4; ++r) {
                const int ss = wr*32 + mt*16 + lg*4 + r;           // 0..63
                const bool mk = (mode == 2) ? (maskp[i0 + ss] != 0) : false;
                #pragma unroll
                for (int nt = 0; nt < 4; ++nt) {
                    float v = acc[mt][nt][r] + bv[nt];
                    if (mode == 2 && !mk) psum[nt] += __expf(v);
                    const int jj = wc*64 + nt*16 + l15;            // 0..127
                    SH[jj*64 + (((ss >> 3) ^ (jj & 7)))*8 + (ss & 7)] = f2bf(v);
                }
            }
        }
        if (mode == 2) {
            const int b = i0 >> 12;
            #pragma unroll
            for (int nt = 0; nt < 4; ++nt) {
                float s = psum[nt];
                s += __shfl_xor(s, 16);
                s += __shfl_xor(s, 32);
                if (lg == 0)
                    atomicAdd(&colsum[b*E_DIM + j0 + wc*64 + nt*16 + l15], s);
            }
        }
        __syncthreads();
        const int b = i0 >> 12, srel = i0 & 4095;
        unsigned short* T = (unsigned short*)outv;
        const int jj = tid >> 1, hf = tid & 1;
        const size_t gbase = ((size_t)(b*1024 + j0 + jj))*4096 + srel;
        #pragma unroll
        for (int c = 0; c < 4; ++c) {
            const int slot = hf*4 + c;
            uint4 u = *(const uint4*)&SH[jj*64 + ((slot ^ (jj & 7)))*8];
            *(uint4*)(T + gbase + slot*8) = u;
        }
        return;
    }

    #pragma unroll
    for (int mt = 0; mt < 2; ++mt) {
        #pragma unroll
        for (int r = 0; r < 4; ++r) {
            float v0 = acc[mt][0][r] + bv[0];
            float v1 = acc[mt][1][r] + bv[1];
            float v2 = acc[mt][2][r] + bv[2];
            float v3 = acc[mt][3][r] + bv[3];
            if (mode == 1) {
                float mx = fmaxf(fmaxf(v0, v1), fmaxf(v2, v3));
                mx = fmaxf(mx, __shfl_xor(mx, 1));
                mx = fmaxf(mx, __shfl_xor(mx, 2));
                mx = fmaxf(mx, __shfl_xor(mx, 4));
                mx = fmaxf(mx, __shfl_xor(mx, 8));
                v0 = __expf(v0 - mx); v1 = __expf(v1 - mx);
                v2 = __expf(v2 - mx); v3 = __expf(v3 - mx);
                float s = v0 + v1 + v2 + v3;
                s += __shfl_xor(s, 1);
                s += __shfl_xor(s, 2);
                s += __shfl_xor(s, 4);
                s += __shfl_xor(s, 8);
                float inv = 1.f / s;
                v0 *= inv; v1 *= inv; v2 *= inv; v3 *= inv;
            }
            const size_t rowo = (size_t)(i0 + wr*32 + mt*16 + lg*4 + r) * E_DIM;
            const int colb = j0 + wc*64 + l15;
            if (OUTF32) {
                float* out = (float*)outv;
                out[rowo + colb     ] = v0;
                out[rowo + colb + 16] = v1;
                out[rowo + colb + 32] = v2;
                out[rowo + colb + 48] = v3;
            } else {
                unsigned short* out = (unsigned short*)outv;
                out[rowo + colb     ] = f2bf(v0);
                out[rowo + colb + 16] = f2bf(v1);
                out[rowo + colb + 32] = f2bf(v2);
                out[rowo + colb + 48] = f2bf(v3);
            }
        }
    }
}

// ---------------------------------------------------------------------------
// Dispatch swizzle (verified r12): panel = (n>>6)*8 + (n&7); j = (n>>3)&7.
// ---------------------------------------------------------------------------

// single-GEMM wrapper (final projection, bf16 A, mode 4). 1D grid 2048.
template<int XF32, int OUTF32>
__global__ __launch_bounds__(256)
void mfma_gemm(const void* __restrict__ Xv, const unsigned short* __restrict__ Wt,
               const float* __restrict__ bias, void* __restrict__ outv,
               const unsigned char* __restrict__ maskp, float* __restrict__ colsum,
               int mode)
{
    __shared__ __align__(16) unsigned short SH[12288];   // 24 KB
    const int n = blockIdx.x;
    const int panel = ((n >> 6) << 3) | (n & 7);    // 0..255
    const int jj = (n >> 3) & 7;
    gemm_core<XF32, OUTF32>(SH, Xv, Wt, bias, outv, maskp, colsum, mode,
                            panel * 64, jj * 128);
}

// fused q/k/v projection: 1D grid 6144; panel 0..767 -> grp, ip
template<int XF32>
__global__ __launch_bounds__(256)
void proj_fused(const void* __restrict__ Xq, const void* __restrict__ Xk,
                const void* __restrict__ Xvv, const unsigned short* __restrict__ Wt,
                const float* __restrict__ bq, const float* __restrict__ bk,
                const float* __restrict__ bv, unsigned short* __restrict__ qn,
                unsigned short* __restrict__ KT, unsigned short* __restrict__ VT,
                const unsigned char* __restrict__ mask, float* __restrict__ colsum)
{
    __shared__ __align__(16) unsigned short SH[12288];
    const int n = blockIdx.x;
    const int panel = ((n >> 6) << 3) | (n & 7);    // 0..767
    const int jj = (n >> 3) & 7;
    const int grp = panel >> 8;
    const int ip  = panel & 255;
    const void* X = (grp == 0) ? Xq : (grp == 1) ? Xk : Xvv;
    const float* bias = (grp == 0) ? bq : (grp == 1) ? bk : bv;
    void* out = (grp == 0) ? (void*)qn : (grp == 1) ? (void*)KT : (void*)VT;
    gemm_core<XF32, 0>(SH, X, Wt + (size_t)grp*1048576, bias, out, mask, colsum,
                       grp + 1, ip * 64, jj * 128);
}

// ---------------------------------------------------------------------------
// context via MFMA: partial[sb][b][h][d][e]; NST 128-s sub-tiles per block.
// grid (SEQ/(NST*128), HEADS, BATCH); NPLANES = SEQ/(NST*128) partial planes.
// ---------------------------------------------------------------------------
template<int NST>
__global__ __launch_bounds__(256)
void context_mfma(const unsigned short* __restrict__ KT,
                  const unsigned short* __restrict__ VT,
                  const unsigned char* __restrict__ mask,
                  float* __restrict__ partial)
{
    __shared__ __align__(16) unsigned short Ks[64*128];
    __shared__ __align__(16) unsigned short Vs[64*128];
    const int sb = blockIdx.x, h = blockIdx.y, b = blockIdx.z;
    const int tid = threadIdx.x, lane = tid & 63, w = tid >> 6;
    const int wr = w >> 1, wc = w & 1;
    const int l15 = lane & 15, lg = lane >> 4;
    const int srow = tid >> 2;
    const int sq0  = (tid & 3) * 4;

    f32x4 acc[2][2];
    #pragma unroll
    for (int m = 0; m < 2; ++m)
        #pragma unroll
        for (int n = 0; n < 2; ++n) {
            f32x4 z = {0.f, 0.f, 0.f, 0.f};
            acc[m][n] = z;
        }

    for (int st = 0; st < NST; ++st) {
        const int s0 = sb*(NST*128) + st*128;
        const unsigned short* kt = KT + ((size_t)(b*1024 + h*64 + srow))*4096 + s0;
        const unsigned short* vt = VT + ((size_t)(b*1024 + h*64 + srow))*4096 + s0;
        const unsigned char*  mp = mask + b*SEQ + s0;
        #pragma unroll
        for (int qi = 0; qi < 4; ++qi) {
            const int slot = sq0 + qi;
            uint4 u = *(const uint4*)(kt + slot*8);
            uint2 mk = *(const uint2*)(mp + slot*8);
            const unsigned char* mb = (const unsigned char*)&mk;
            const unsigned short* us = (const unsigned short*)&u;
            float e[8];
            #pragma unroll
            for (int i = 0; i < 8; ++i)
                e[i] = mb[i] ? 0.f : __expf(bf2f(us[i]));
            uint4 p;
            p.x = pack2bf(e[0], e[1]);
            p.y = pack2bf(e[2], e[3]);
            p.z = pack2bf(e[4], e[5]);
            p.w = pack2bf(e[6], e[7]);
            *(uint4*)&Ks[srow*128 + ((slot ^ (srow & 15)))*8] = p;
            uint4 uv = *(const uint4*)(vt + slot*8);
            *(uint4*)&Vs[srow*128 + ((slot ^ (srow & 15)))*8] = uv;
        }
        __syncthreads();
        #pragma unroll
        for (int ks = 0; ks < 4; ++ks) {
            bf16x8 a[2], bq[2];
            #pragma unroll
            for (int mt = 0; mt < 2; ++mt) {
                const int d = wr*32 + mt*16 + l15;
                a[mt] = *(const bf16x8*)&Ks[d*128 + (((ks*4+lg) ^ (d & 15)))*8];
            }
            #pragma unroll
            for (int nt = 0; nt < 2; ++nt) {
                const int e = wc*32 + nt*16 + l15;
                bq[nt] = *(const bf16x8*)&Vs[e*128 + (((ks*4+lg) ^ (e & 15)))*8];
            }
            #pragma unroll
            for (int mt = 0; mt < 2; ++mt)
                #pragma unroll
                for (int nt = 0; nt < 2; ++nt)
                    acc[mt][nt] = __builtin_amdgcn_mfma_f32_16x16x32_bf16(a[mt], bq[nt], acc[mt][nt], 0, 0, 0);
        }
        __syncthreads();
    }
    float* pp = partial + (size_t)sb*(BATCH*HEADS*4096) + ((size_t)(b*HEADS + h))*4096;
    #pragma unroll
    for (int mt = 0; mt < 2; ++mt)
        #pragma unroll
        for (int nt = 0; nt < 2; ++nt)
            #pragma unroll
            for (int r = 0; r < 4; ++r) {
                const int d = wr*32 + mt*16 + lg*4 + r;
                const int e = wc*32 + nt*16 + l15;
                pp[d*64 + e] = acc[mt][nt][r];
            }
}

// ---------------------------------------------------------------------------
template<int NPLANES>
__global__ __launch_bounds__(256)
void reduce_ctx(const float* __restrict__ partial, float* __restrict__ ctx)
{
    const int i = blockIdx.x * 256 + threadIdx.x;
    const float4* p = (const float4*)partial;
    float4 s = p[i];
    #pragma unroll
    for (int q = 1; q < NPLANES; ++q) {
        float4 u = p[(size_t)q*65536 + i];
        s.x += u.x; s.y += u.y; s.z += u.z; s.w += u.w;
    }
    ((float4*)ctx)[i] = s;
}

// ---------------------------------------------------------------------------
// G_t[b][j][h*64+d] = sum_e WtO[j][h*64+e] * (ctx[b,h,d,e]/colsum[b,h,d])
// ---------------------------------------------------------------------------
__global__ __launch_bounds__(256)
void g_kernel(const unsigned short* __restrict__ WtO, const float* __restrict__ ctx,
              const float* __restrict__ colsum, unsigned short* __restrict__ Gt)
{
    __shared__ __align__(16) unsigned short Aw[128*64];
    __shared__ __align__(16) unsigned short Bc[64*64];
    const int jt = blockIdx.x, h = blockIdx.y, b = blockIdx.z;
    const int tid = threadIdx.x, lane = tid & 63, w = tid >> 6;
    const int l15 = lane & 15, lg = lane >> 4;
    const int j0 = jt * 128;

    {
        const int ar = tid >> 1, aq0 = (tid & 1) * 4;
        #pragma unroll
        for (int qi = 0; qi < 4; ++qi) {
            const int slot = aq0 + qi;
            uint4 u = *(const uint4*)(WtO + (size_t)(j0 + ar)*E_DIM + h*64 + slot*8);
            *(uint4*)&Aw[ar*64 + ((slot ^ (ar & 7)))*8] = u;
        }
    }
    {
        const int br = tid >> 2, bq0 = (tid & 3) * 2;
        const float inv = 1.f / colsum[b*E_DIM + h*64 + br];
        #pragma unroll
        for (int qi = 0; qi < 2; ++qi) {
            const int slot = bq0 + qi;
            const float* cp = ctx + (((size_t)(b*HEADS + h))*64 + br)*64 + slot*8;
            float4 c0 = *(const float4*)cp;
            float4 c1 = *(const float4*)(cp + 4);
            uint4 p;
            p.x = pack2bf(c0.x*inv, c0.y*inv);
            p.y = pack2bf(c0.z*inv, c0.w*inv);
            p.z = pack2bf(c1.x*inv, c1.y*inv);
            p.w = pack2bf(c1.z*inv, c1.w*inv);
            *(uint4*)&Bc[br*64 + ((slot ^ (br & 7)))*8] = p;
        }
    }
    __syncthreads();

    f32x4 acc[2][4];
    #pragma unroll
    for (int m = 0; m < 2; ++m)
        #pragma unroll
        for (int n = 0; n < 4; ++n) {
            f32x4 z = {0.f, 0.f, 0.f, 0.f};
            acc[m][n] = z;
        }
    #pragma unroll
    for (int ks = 0; ks < 2; ++ks) {
        bf16x8 a[2], bv[4];
        #pragma unroll
        for (int mt = 0; mt < 2; ++mt) {
            const int jr = w*32 + mt*16 + l15;
            a[mt] = *(const bf16x8*)&Aw[jr*64 + (((ks*4+lg) ^ (jr & 7)))*8];
        }
        #pragma unroll
        for (int nt = 0; nt < 4; ++nt) {
            const int d = nt*16 + l15;
            bv[nt] = *(const bf16x8*)&Bc[d*64 + (((ks*4+lg) ^ (d & 7)))*8];
        }
        #pragma unroll
        for (int mt = 0; mt < 2; ++mt)
            #pragma unroll
            for (int nt = 0; nt < 4; ++nt)
                acc[mt][nt] = __builtin_amdgcn_mfma_f32_16x16x32_bf16(a[mt], bv[nt], acc[mt][nt], 0, 0, 0);
    }
    #pragma unroll
    for (int mt = 0; mt < 2; ++mt)
        #pragma unroll
        for (int nt = 0; nt < 4; ++nt)
            #pragma unroll
            for (int r = 0; r < 4; ++r) {
                const int j = j0 + w*32 + mt*16 + lg*4 + r;
                const int d = nt*16 + l15;
                Gt[(size_t)b*1048576 + (size_t)j*E_DIM + h*64 + d] = f2bf(acc[mt][nt][r]);
            }
}

// ---------------------------------------------------------------------------
extern "C" void kernel_launch(void* const* d_in, const int* in_sizes, int n_in,
                              void* d_out, int out_size, void* d_ws, size_t ws_size,
                              hipStream_t stream)
{
    const float* query = (const float*)d_in[0];
    const float* key   = (const float*)d_in[1];
    const float* value = (const float*)d_in[2];
    const unsigned char* mask = (const unsigned char*)d_in[3];
    const float* Wq  = (const float*)d_in[4];
    const float* bq  = (const float*)d_in[5];
    const float* Wk  = (const float*)d_in[6];
    const float* bk  = (const float*)d_in[7];
    const float* Wv  = (const float*)d_in[8];
    const float* bv_ = (const float*)d_in[9];
    const float* qla = (const float*)d_in[10];
    const float* qlb = (const float*)d_in[11];
    const float* kla = (const float*)d_in[12];
    const float* klb = (const float*)d_in[13];
    const float* vla = (const float*)d_in[14];
    const float* vlb = (const float*)d_in[15];
    const float* Wo  = (const float*)d_in[16];
    const float* bo  = (const float*)d_in[17];

    const size_t NEEDED_A = 118505472ULL;                 // base layout (proven)
    const size_t NEEDED_B = NEEDED_A + 3ULL*33554432ULL;  // + qbf/kbf/vbf
    if (ws_size < NEEDED_A) {
        ws_sentinel<<<1, 256, 0, stream>>>((float*)d_out, (float)(ws_size >> 20));
        return;
    }

    char* ws = (char*)d_ws;
    unsigned short* Wt      = (unsigned short*)(ws + 0);          // 8 MB
    unsigned short* KT      = (unsigned short*)(ws + 8388608);    // 32 MB [b][1024][4096]
    unsigned short* VT      = (unsigned short*)(ws + 41943040);   // 32 MB
    unsigned short* qn      = (unsigned short*)(ws + 75497472);   // 32 MB
    float*          partial = (float*)(ws + 109051904);           // 8 MB (path A; overlays Gt)
    unsigned short* Gt      = (unsigned short*)(ws + 109051904);  // 8 MB
    float*          colsum  = (float*)(ws + 117440512);           // 16 KB
    float*          ctx     = (float*)(ws + 117456896);           // 1 MB
    unsigned short* qbf     = (unsigned short*)(ws + 118505472);  // 32 MB (path B)
    unsigned short* kbf     = (unsigned short*)(ws + 152059904);  // 32 MB
    unsigned short* vbf     = (unsigned short*)(ws + 185614336);  // 32 MB
    float*          part16  = (float*)(ws + 118505472);           // 16 MB (path B; qbf dead after proj)

    prep_weights_t<<<dim3(32, 32, 4), 256, 0, stream>>>(Wq, Wk, Wv, Wo,
                                                        qla, qlb, kla, klb, vla, vlb, Wt);
    if (ws_size >= NEEDED_B) {
        // path B: one-time f32->bf16 convert (+colsum zero), all-bf16 GEMMs
        convert_bf16<<<2048, 256, 0, stream>>>(query, key, value, qbf, kbf, vbf, colsum);
        proj_fused<0><<<6144, 256, 0, stream>>>(qbf, kbf, vbf, Wt,
                                                bq, bk, bv_, qn, KT, VT, mask, colsum);
        context_mfma<2><<<dim3(16, HEADS, BATCH), 256, 0, stream>>>(KT, VT, mask, part16);
        reduce_ctx<16><<<256, 256, 0, stream>>>(part16, ctx);
    } else {
        // path A: f32 A staged in-GEMM via cvt_pk (r12-class fallback)
        zero_colsum<<<16, 256, 0, stream>>>(colsum);
        proj_fused<1><<<6144, 256, 0, stream>>>(query, key, value, Wt,
                                                bq, bk, bv_, qn, KT, VT, mask, colsum);
        context_mfma<4><<<dim3(8, HEADS, BATCH), 256, 0, stream>>>(KT, VT, mask, partial);
        reduce_ctx<8><<<256, 256, 0, stream>>>(partial, ctx);
    }
    g_kernel<<<dim3(8, HEADS, BATCH), 256, 0, stream>>>(Wt + 3145728, ctx, colsum, Gt);
    mfma_gemm<0, 1><<<2048, 256, 0, stream>>>(qn, Gt, bo, (float*)d_out,
                                              nullptr, nullptr, 4);
}